// Round 10
// baseline (208.564 us; speedup 1.0000x reference)
//
#include <hip/hip_runtime.h>

#define HW_    56
#define C_     128
#define SHIFT_ 3
#define NH_    4
#define NT_    49

typedef __attribute__((ext_vector_type(8))) __bf16 bf16x8;
typedef __attribute__((ext_vector_type(4))) float  f32x4;
typedef __attribute__((ext_vector_type(4))) short  s16x4;

// d_ws layout:
//   shorts [0, 65536)      : wT[384][128] (oc-major) then wpT[128][128]
//   bytes  [131072, +3.2MB): f32 cb[wpos=64][h=4][q=49][k=64]  (bias+mask, post-softmax)
#define WS_CB_BYTE  131072
#define CB_ELEMS    (64 * 4 * 49 * 64)

// LDS 29440 B -> 5 blocks/CU @ 256 thr (147KB/160KB).
// [0, 12544):  X [16 g][49 tok][16B] stride 784, identity (conflict-free:
//              fixed g per quarter-wave, rows contiguous). Reads to row 63
//              spill into pad/V region: in-bounds garbage feeding discarded
//              columns only. After b2, X2 (attn out) overlays (g = d>>3).
// [12800, 29184): V per head h at VB+h*4096, FRAG-LINEAR for x16 PV:
//              frag(mtd*4+kt) = 512B, element = lane*8 + j*2. va reads are
//              fully linear ds_read_b64 (zero conflict). Keys 49..63
//              ZERO-FILLED at write (PV reduction axis: NaN*0=NaN!).
// [29184, 29380): int toff[49] (token -> gh*56+gw, rolled).
// Q, K, P: REGISTER-RESIDENT (x16 MFMA k=4lg+j matches C-layout 4-chunks).
// R10 spill diet (R9 spilled ~110MB scratch/dispatch): X2 scatter moved
// inside the nt loop (o[2][4]->o2 per-nt, -24 regs), bfpR hoist removed
// (-32 regs), launch_bounds (256,5).
#define XB    0
#define VB    12800
#define TOFFB 29184
#define SMEMB 29440

__device__ __forceinline__ int q4(int g, int tok) { return g * 784 + (tok << 4); }
__device__ __forceinline__ unsigned short bfbits(float f) {
    __bf16 h = (__bf16)f;
    union { __bf16 b; unsigned short u; } c; c.b = h; return c.u;
}
__device__ __forceinline__ int region(int c) { return c < 49 ? 0 : (c < 53 ? 1 : 2); }

// ---- prep 1: transpose + bf16-convert weights ----
__global__ void prep_weights(const float* __restrict__ wq, const float* __restrict__ wp,
                             unsigned short* __restrict__ ws) {
    int i = blockIdx.x * 256 + threadIdx.x;
    if (i < 49152) {
        int oc = i >> 7, ic = i & 127;
        ws[i] = bfbits(wq[ic * 384 + oc]);
    } else if (i < 65536) {
        int j = i - 49152;
        int oc = j >> 7, ic = j & 127;
        ws[i] = bfbits(wp[ic * 128 + oc]);
    }
}

// ---- prep 2: combined post-softmax bias + shifted-window mask ----
__global__ void prep_bias(const float* __restrict__ rel_table, float* __restrict__ cb) {
    int i = blockIdx.x * 256 + threadIdx.x;
    if (i >= CB_ELEMS) return;
    int k = i & 63;
    int t = i >> 6;          // (wpos*4 + h)*49 + q
    int q = t % 49;
    int u = t / 49;
    int h = u & 3;
    int wpos = u >> 2;
    float v = 0.f;
    if (k < 49) {
        int iq = q / 7, jq = q - 7 * iq;
        int ik = k / 7, jk = k - 7 * ik;
        int wi = wpos >> 3, wj = wpos & 7;
        v = rel_table[((iq - ik + 6) * 13 + (jq - jk + 6)) * NH_ + h];
        int rq = region(wi * 7 + iq) * 3 + region(wj * 7 + jq);
        int rk = region(wi * 7 + ik) * 3 + region(wj * 7 + jk);
        if (rq != rk) v -= 100.0f;
    }
    cb[i] = v;
}

__global__ __launch_bounds__(256, 5)
void swin_fused(const float* __restrict__ x,
                const float* __restrict__ b_qkv,
                const float* __restrict__ b_proj,
                const unsigned short* __restrict__ wsb,
                const float* __restrict__ cb,
                float* __restrict__ out)
{
    extern __shared__ char smc[];
    const __bf16* wt  = (const __bf16*)wsb;           // [384][128]
    const __bf16* wpt = (const __bf16*)(wsb + 49152); // [128][128]

    const int tid = threadIdx.x;
    const int bn  = blockIdx.x;
    const int b   = bn >> 6;
    const int wi  = (bn >> 3) & 7;
    const int wj  = bn & 7;

    const int w  = tid >> 6;        // wave id = head id
    const int lr = tid & 15;        // lane % 16
    const int lg = (tid & 63) >> 4; // lane / 16

    // token -> rolled spatial offset table (read after b3 by epilogue)
    if (tid < NT_) {
        const int i1 = tid / 7, j1 = tid - 7 * i1;
        int gh = wi * 7 + i1 + SHIFT_; if (gh >= HW_) gh -= HW_;
        int gw = wj * 7 + j1 + SHIFT_; if (gw >= HW_) gw -= HW_;
        ((int*)(smc + TOFFB))[tid] = gh * HW_ + gw;
    }

    // ---------------- phase 1: x -> X (bf16 frag-order, 49 rows) ----------------
    for (int idx = tid; idx < 49 * 16; idx += 256) {
        const int g = idx & 15, tok = idx >> 4;
        const int i1 = tok / 7, j1 = tok - 7 * i1;
        int gh = wi * 7 + i1 + SHIFT_; if (gh >= HW_) gh -= HW_;
        int gw = wj * 7 + j1 + SHIFT_; if (gw >= HW_) gw -= HW_;
        const float* px = x + (((size_t)(b * HW_ + gh)) * HW_ + gw) * C_ + g * 8;
        float4 a0 = *(const float4*)(px);
        float4 a1 = *(const float4*)(px + 4);
        union { bf16x8 v; __bf16 e[8]; } u;
        u.e[0] = (__bf16)a0.x; u.e[1] = (__bf16)a0.y;
        u.e[2] = (__bf16)a0.z; u.e[3] = (__bf16)a0.w;
        u.e[4] = (__bf16)a1.x; u.e[5] = (__bf16)a1.y;
        u.e[6] = (__bf16)a1.z; u.e[7] = (__bf16)a1.w;
        *(bf16x8*)(smc + XB + q4(g, tok)) = u.v;
    }
    __syncthreads();  // b1: X (and toff) ready

    // ---------------- phase 2: QKV, wave w owns head w; Q/K -> registers ----------------
    // pass0: {2w (q d0-15), 2w+1 (q d16-31), 16+2w (v d0-15)}
    // pass1: {8+2w (k d0-15), 8+2w+1 (k d16-31), 16+2w+1 (v d16-31)}
    const float qscale = 0.17677669529663687f;
    const int vb = VB + w * 4096;
    s16x4 qf[2][4], ka[2][4];   // x16 fragments: elem j = key/d offset 4*lg+j

    #pragma unroll
    for (int pass = 0; pass < 2; ++pass) {
        const int ma = pass * 8 + 2 * w;
        const int mv = 16 + 2 * w + pass;
        f32x4 acc[3][4];
        #pragma unroll
        for (int i = 0; i < 3; ++i) {
            const int mt = (i < 2) ? (ma + i) : mv;
            const f32x4 bv = *(const f32x4*)(b_qkv + mt * 16 + lg * 4);
            #pragma unroll
            for (int nt = 0; nt < 4; ++nt) acc[i][nt] = bv;
        }
        #pragma unroll
        for (int ks = 0; ks < 4; ++ks) {
            bf16x8 bfr[4];
            #pragma unroll
            for (int nt = 0; nt < 4; ++nt)   // rows>=49: in-bounds garbage, cols discarded
                bfr[nt] = *(const bf16x8*)(smc + XB + q4(ks * 4 + lg, nt * 16 + lr));
            #pragma unroll
            for (int i = 0; i < 3; ++i) {
                const int mt = (i < 2) ? (ma + i) : mv;
                bf16x8 afr = *(const bf16x8*)(wt + (mt * 16 + lr) * 128 + ks * 32 + lg * 8);
                #pragma unroll
                for (int nt = 0; nt < 4; ++nt)
                    acc[i][nt] = __builtin_amdgcn_mfma_f32_16x16x32_bf16(afr, bfr[nt], acc[i][nt], 0, 0, 0);
            }
        }
        // pack q (pass0, scaled) / k (pass1) directly into x16 fragments
        #pragma unroll
        for (int kt = 0; kt < 2; ++kt)
            #pragma unroll
            for (int nt = 0; nt < 4; ++nt) {
                union { s16x4 v; __bf16 e[4]; } u;
                #pragma unroll
                for (int r = 0; r < 4; ++r)
                    u.e[r] = (__bf16)(pass ? acc[kt][nt][r] : acc[kt][nt][r] * qscale);
                if (pass) ka[kt][nt] = u.v; else qf[kt][nt] = u.v;
            }
        // V scatter, frag-linear; keys 49..63 ZERO (PV reduction axis)
        #pragma unroll
        for (int nt = 0; nt < 4; ++nt) {
            const int key = nt * 16 + lr;
            #pragma unroll
            for (int r = 0; r < 4; ++r) {
                const unsigned short val =
                    (key < NT_) ? bfbits(acc[2][nt][r]) : (unsigned short)0;
                *(unsigned short*)(smc + vb + (pass * 4 + nt) * 512
                      + ((lg * 4 + r) + ((lr >> 2) << 4)) * 8 + ((lr & 3) << 1)) = val;
            }
        }
    }
    __syncthreads();  // b2: all X reads done -> X2 may overlay X

    // ---------------- phase 3: attention, fully wave-private ----------------
    // va: 8 linear ds_read_b64 (own V, same-wave write->read ordered by lgkmcnt)
    s16x4 va[2][4];
    #pragma unroll
    for (int mtd = 0; mtd < 2; ++mtd)
        #pragma unroll
        for (int kt = 0; kt < 4; ++kt)
            va[mtd][kt] = *(const s16x4*)(smc + vb + (mtd * 4 + kt) * 512 + (tid & 63) * 8);

    const float* cbw = cb + (((size_t)(wi * 8 + wj) * 4 + w) * 49) * 64;

    #pragma unroll
    for (int nt = 0; nt < 4; ++nt) {
        // S^T tile column: keys x q for this q-tile (K=16 MFMAs, reg operands)
        f32x4 sn[4];
        #pragma unroll
        for (int mt = 0; mt < 4; ++mt) {
            f32x4 z = {0.f, 0.f, 0.f, 0.f};
            z = __builtin_amdgcn_mfma_f32_16x16x16bf16_1k(ka[0][mt], qf[0][nt], z, 0, 0, 0);
            sn[mt] = __builtin_amdgcn_mfma_f32_16x16x16bf16_1k(ka[1][mt], qf[1][nt], z, 0, 0, 0);
        }
        // softmax over keys (valid: keys 0..48; key = mt*16 + lg*4 + r)
        float mx = -3.0e38f;
        #pragma unroll
        for (int mt = 0; mt < 3; ++mt)
            #pragma unroll
            for (int r = 0; r < 4; ++r) mx = fmaxf(mx, sn[mt][r]);
        if (lg == 0) mx = fmaxf(mx, sn[3][0]);
        mx = fmaxf(mx, __shfl_xor(mx, 16));
        mx = fmaxf(mx, __shfl_xor(mx, 32));
        float sum = 0.f;
        #pragma unroll
        for (int mt = 0; mt < 3; ++mt)
            #pragma unroll
            for (int r = 0; r < 4; ++r) {
                const float e = __expf(sn[mt][r] - mx);
                sn[mt][r] = e; sum += e;
            }
        {
            const float e = (lg == 0) ? __expf(sn[3][0] - mx) : 0.f;
            sn[3][0] = e;
            sum += e;
        }
        sum += __shfl_xor(sum, 16);
        sum += __shfl_xor(sum, 32);
        const float rs = 1.0f / sum;

        const int q  = nt * 16 + lr;
        const int qc = (q < NT_) ? q : 48;
        const float* cbq = cbw + qc * 64;

        // post-softmax bias+mask, pack P directly into x16 B-fragments (NO LDS)
        s16x4 pf[4];
        #pragma unroll
        for (int mt = 0; mt < 4; ++mt) {
            const f32x4 bv = *(const f32x4*)(cbq + mt * 16 + lg * 4);
            union { s16x4 v; __bf16 e[4]; } u;
            #pragma unroll
            for (int r = 0; r < 4; ++r) {
                const bool valid = (mt < 3) || (lg == 0 && r == 0);
                const float p = fmaf(sn[mt][r], rs, bv[r]);
                u.e[r] = valid ? (__bf16)p : (__bf16)0.0f;
            }
            pf[mt] = u.v;
        }
        // PV accumulate (K=16 over 4 key-tiles), per-nt accumulators only
        f32x4 o0 = {0.f, 0.f, 0.f, 0.f}, o1 = {0.f, 0.f, 0.f, 0.f};
        #pragma unroll
        for (int kt = 0; kt < 4; ++kt) {
            o0 = __builtin_amdgcn_mfma_f32_16x16x16bf16_1k(va[0][kt], pf[kt], o0, 0, 0, 0);
            o1 = __builtin_amdgcn_mfma_f32_16x16x16bf16_1k(va[1][kt], pf[kt], o1, 0, 0, 0);
        }
        // X2 scatter for this nt (own head's g-range; X region dead post-b2)
        if (q < NT_) {
            const int inner = (lg & 1) << 3;
            union { short4 s4; __bf16 e[4]; } pk0, pk1;
            #pragma unroll
            for (int r = 0; r < 4; ++r) { pk0.e[r] = (__bf16)o0[r]; pk1.e[r] = (__bf16)o1[r]; }
            *(short4*)(smc + XB + q4(w * 4 + 0 + (lg >> 1), q) + inner) = pk0.s4;
            *(short4*)(smc + XB + q4(w * 4 + 2 + (lg >> 1), q) + inner) = pk1.s4;
        }
    }
    __syncthreads();  // b3: all heads' X2 complete

    // ---------------- phase 4: proj = X2 @ Wp + store ----------------
    {
        const int* toff = (const int*)(smc + TOFFB);
        f32x4 pacc[4][2];
        #pragma unroll
        for (int ntl = 0; ntl < 2; ++ntl) {
            const float bv = b_proj[(w * 2 + ntl) * 16 + lr];
            #pragma unroll
            for (int mt = 0; mt < 4; ++mt) {
                f32x4 v = {bv, bv, bv, bv};
                pacc[mt][ntl] = v;
            }
        }
        #pragma unroll
        for (int ks = 0; ks < 4; ++ks) {
            bf16x8 af[4];
            #pragma unroll
            for (int mt = 0; mt < 4; ++mt)
                af[mt] = *(const bf16x8*)(smc + XB + q4(ks * 4 + lg, mt * 16 + lr));
            #pragma unroll
            for (int ntl = 0; ntl < 2; ++ntl) {
                const bf16x8 bfp = *(const bf16x8*)(wpt + ((w * 2 + ntl) * 16 + lr) * 128 + ks * 32 + lg * 8);
                #pragma unroll
                for (int mt = 0; mt < 4; ++mt)
                    pacc[mt][ntl] = __builtin_amdgcn_mfma_f32_16x16x32_bf16(af[mt], bfp, pacc[mt][ntl], 0, 0, 0);
            }
        }
        #pragma unroll
        for (int mt = 0; mt < 4; ++mt)
            #pragma unroll
            for (int r = 0; r < 4; ++r) {
                const int tok = mt * 16 + lg * 4 + r;
                if (tok < NT_) {
                    float* po = out + (((size_t)b * (HW_ * HW_)) + toff[tok]) * C_;
                    #pragma unroll
                    for (int ntl = 0; ntl < 2; ++ntl)
                        po[(w * 2 + ntl) * 16 + lr] = pacc[mt][ntl][r];
                }
            }
    }
}

extern "C" void kernel_launch(void* const* d_in, const int* in_sizes, int n_in,
                              void* d_out, int out_size, void* d_ws, size_t ws_size,
                              hipStream_t stream) {
    const float* x      = (const float*)d_in[0];
    const float* w_qkv  = (const float*)d_in[1];
    const float* b_qkv  = (const float*)d_in[2];
    const float* w_proj = (const float*)d_in[3];
    const float* b_proj = (const float*)d_in[4];
    const float* rel    = (const float*)d_in[5];
    float* outp = (float*)d_out;
    unsigned short* wsb = (unsigned short*)d_ws;
    float* cbp = (float*)((char*)d_ws + WS_CB_BYTE);

    hipLaunchKernelGGL(prep_weights, dim3(256), dim3(256), 0, stream, w_qkv, w_proj, wsb);
    hipLaunchKernelGGL(prep_bias, dim3((CB_ELEMS + 255) / 256), dim3(256), 0, stream, rel, cbp);
    hipLaunchKernelGGL(swin_fused, dim3(4096), dim3(256), SMEMB, stream,
                       x, b_qkv, b_proj, wsb, cbp, outp);
}

// Round 11
// 180.147 us; speedup vs baseline: 1.1577x; 1.1577x over previous
//
#include <hip/hip_runtime.h>

#define HW_    56
#define C_     128
#define SHIFT_ 3
#define NH_    4
#define NT_    49

typedef __attribute__((ext_vector_type(8))) __bf16 bf16x8;
typedef __attribute__((ext_vector_type(4))) float  f32x4;
typedef __attribute__((ext_vector_type(4))) short  s16x4;

// d_ws layout:
//   shorts [0, 65536)      : wT[384][128] (oc-major) then wpT[128][128]
//   bytes  [131072, +3.2MB): f32 cb[wpos=64][h=4][q=49][k=64]  (bias+mask, post-softmax)
#define WS_CB_BYTE  131072
#define CB_ELEMS    (64 * 4 * 49 * 64)

// LDS 30336 B -> 5 blocks/CU @ 256 thr (151.7KB / 160KB), 20 waves/CU.
// [0, 13728) X/V region:
//   phases 1-2: X [16 g][49 tok][16B] stride 784 identity (fixed g per
//     quarter-wave -> conflict-free). Reads to tok 63 reach byte 12784 < 13728:
//     in-bounds garbage feeding discarded cols only.
//   after b2: V per head h at h*3432: [13 kg][32 d][8B], kg stride 264
//     (264/4=66 = 2 mod 32 -> the 4 kg groups touched by a quarter-wave land
//     on distinct bank pairs -> b16 scatter conflict-free). Element =
//     kg*264 + d*8 + (key&3)*2. va reads: fixed kg per quarter, 16 lanes x 8B
//     linear. Keys 49..51 ZERO-FILLED, kg reads clamped to 12 (PV reduction
//     axis: NaN*0=NaN — only P=0 on keys>=49 protects us, so V must be 0 too).
// [13728, 30112) K region (4 heads x 4096): [8 dg][64 key][8B]; written and
//   read by the OWN head's wave only (b64, conflict-free). After b3, X2
//   (attn out) overlays as [16 g][49 tok][16B] stride 784 (cross-wave -> b3).
// [30112, 30308): int toff[49].
// Q: REGISTER-RESIDENT x16 fragments (C-layout 4-chunk == x16 k-chunk).
// R11 vs R9/R10: only Q in regs (not K/V) -> no spill; 3x2-tile phase 2.
#define XB    0
#define VHD   3432
#define KB    13728
#define TOFFB 30112
#define SMEMB 30336

__device__ __forceinline__ int q4(int g, int tok) { return g * 784 + (tok << 4); }
__device__ __forceinline__ unsigned short bfbits(float f) {
    __bf16 h = (__bf16)f;
    union { __bf16 b; unsigned short u; } c; c.b = h; return c.u;
}
__device__ __forceinline__ int region(int c) { return c < 49 ? 0 : (c < 53 ? 1 : 2); }

// ---- prep 1: transpose + bf16-convert weights ----
__global__ void prep_weights(const float* __restrict__ wq, const float* __restrict__ wp,
                             unsigned short* __restrict__ ws) {
    int i = blockIdx.x * 256 + threadIdx.x;
    if (i < 49152) {
        int oc = i >> 7, ic = i & 127;
        ws[i] = bfbits(wq[ic * 384 + oc]);
    } else if (i < 65536) {
        int j = i - 49152;
        int oc = j >> 7, ic = j & 127;
        ws[i] = bfbits(wp[ic * 128 + oc]);
    }
}

// ---- prep 2: combined post-softmax bias + shifted-window mask ----
__global__ void prep_bias(const float* __restrict__ rel_table, float* __restrict__ cb) {
    int i = blockIdx.x * 256 + threadIdx.x;
    if (i >= CB_ELEMS) return;
    int k = i & 63;
    int t = i >> 6;          // (wpos*4 + h)*49 + q
    int q = t % 49;
    int u = t / 49;
    int h = u & 3;
    int wpos = u >> 2;
    float v = 0.f;
    if (k < 49) {
        int iq = q / 7, jq = q - 7 * iq;
        int ik = k / 7, jk = k - 7 * ik;
        int wi = wpos >> 3, wj = wpos & 7;
        v = rel_table[((iq - ik + 6) * 13 + (jq - jk + 6)) * NH_ + h];
        int rq = region(wi * 7 + iq) * 3 + region(wj * 7 + jq);
        int rk = region(wi * 7 + ik) * 3 + region(wj * 7 + jk);
        if (rq != rk) v -= 100.0f;
    }
    cb[i] = v;
}

__global__ __launch_bounds__(256, 5)
void swin_fused(const float* __restrict__ x,
                const float* __restrict__ b_qkv,
                const float* __restrict__ b_proj,
                const unsigned short* __restrict__ wsb,
                const float* __restrict__ cb,
                float* __restrict__ out)
{
    extern __shared__ char smc[];
    const __bf16* wt  = (const __bf16*)wsb;           // [384][128]
    const __bf16* wpt = (const __bf16*)(wsb + 49152); // [128][128]

    const int tid = threadIdx.x;
    const int bn  = blockIdx.x;
    const int b   = bn >> 6;
    const int wi  = (bn >> 3) & 7;
    const int wj  = bn & 7;

    const int w  = tid >> 6;        // wave id = head id
    const int lr = tid & 15;        // lane % 16
    const int lg = (tid & 63) >> 4; // lane / 16

    // token -> rolled spatial offset table (read after b4 by epilogue)
    if (tid < NT_) {
        const int i1 = tid / 7, j1 = tid - 7 * i1;
        int gh = wi * 7 + i1 + SHIFT_; if (gh >= HW_) gh -= HW_;
        int gw = wj * 7 + j1 + SHIFT_; if (gw >= HW_) gw -= HW_;
        ((int*)(smc + TOFFB))[tid] = gh * HW_ + gw;
    }

    // ---------------- phase 1: x -> X (bf16 frag-order, 49 rows) ----------------
    for (int idx = tid; idx < 49 * 16; idx += 256) {
        const int g = idx & 15, tok = idx >> 4;
        const int i1 = tok / 7, j1 = tok - 7 * i1;
        int gh = wi * 7 + i1 + SHIFT_; if (gh >= HW_) gh -= HW_;
        int gw = wj * 7 + j1 + SHIFT_; if (gw >= HW_) gw -= HW_;
        const float* px = x + (((size_t)(b * HW_ + gh)) * HW_ + gw) * C_ + g * 8;
        float4 a0 = *(const float4*)(px);
        float4 a1 = *(const float4*)(px + 4);
        union { bf16x8 v; __bf16 e[8]; } u;
        u.e[0] = (__bf16)a0.x; u.e[1] = (__bf16)a0.y;
        u.e[2] = (__bf16)a0.z; u.e[3] = (__bf16)a0.w;
        u.e[4] = (__bf16)a1.x; u.e[5] = (__bf16)a1.y;
        u.e[6] = (__bf16)a1.z; u.e[7] = (__bf16)a1.w;
        *(bf16x8*)(smc + XB + q4(g, tok)) = u.v;
    }
    __syncthreads();  // b1: X (and toff) ready

    // ---------------- phase 2: QKV, wave w = head w, 3 passes x 2 tiles ----------------
    // pass0: q tiles 2w, 2w+1 -> qf regs (x16 frags). pass1: k tiles 8+2w,
    // 8+2w+1 -> K LDS. pass2: v tiles 16+2w, 16+2w+1 -> accV regs (to b2).
    const float qscale = 0.17677669529663687f;
    const int kbh = KB + w * 4096;
    const int vbh = XB + w * VHD;
    s16x4 qf[2][4];
    f32x4 accV[2][4];

    #pragma unroll
    for (int pass = 0; pass < 3; ++pass) {
        const int mt0 = pass * 8 + 2 * w;
        f32x4 acc[2][4];
        #pragma unroll
        for (int i = 0; i < 2; ++i) {
            const f32x4 bv = *(const f32x4*)(b_qkv + (mt0 + i) * 16 + lg * 4);
            #pragma unroll
            for (int nt = 0; nt < 4; ++nt) acc[i][nt] = bv;
        }
        #pragma unroll
        for (int ks = 0; ks < 4; ++ks) {
            bf16x8 bfr[4];
            #pragma unroll
            for (int nt = 0; nt < 4; ++nt)   // rows>=49: in-bounds garbage, cols discarded
                bfr[nt] = *(const bf16x8*)(smc + XB + q4(ks * 4 + lg, nt * 16 + lr));
            #pragma unroll
            for (int i = 0; i < 2; ++i) {
                bf16x8 afr = *(const bf16x8*)(wt + ((mt0 + i) * 16 + lr) * 128 + ks * 32 + lg * 8);
                #pragma unroll
                for (int nt = 0; nt < 4; ++nt)
                    acc[i][nt] = __builtin_amdgcn_mfma_f32_16x16x32_bf16(afr, bfr[nt], acc[i][nt], 0, 0, 0);
            }
        }
        if (pass == 0) {            // Q -> x16 fragments (d = 16*i + 4*lg + r)
            #pragma unroll
            for (int i = 0; i < 2; ++i)
                #pragma unroll
                for (int nt = 0; nt < 4; ++nt) {
                    union { s16x4 v; __bf16 e[4]; } u;
                    #pragma unroll
                    for (int r = 0; r < 4; ++r) u.e[r] = (__bf16)(acc[i][nt][r] * qscale);
                    qf[i][nt] = u.v;
                }
        } else if (pass == 1) {     // K -> LDS [dg][key][8B], own head, b64 stores
            #pragma unroll
            for (int i = 0; i < 2; ++i) {
                const int dg = 4 * i + lg;
                #pragma unroll
                for (int nt = 0; nt < 4; ++nt) {
                    const int key = nt * 16 + lr;
                    union { short4 s4; __bf16 e[4]; } pk;
                    #pragma unroll
                    for (int r = 0; r < 4; ++r) pk.e[r] = (__bf16)acc[i][nt][r];
                    *(short4*)(smc + kbh + dg * 512 + key * 8) = pk.s4;
                }
            }
        } else {                    // V: hold in regs until b2
            #pragma unroll
            for (int i = 0; i < 2; ++i)
                #pragma unroll
                for (int nt = 0; nt < 4; ++nt) accV[i][nt] = acc[i][nt];
        }
    }
    __syncthreads();  // b2: all X reads done -> V may overlay X region

    // V scatter (own head). Keys 49..51 ZERO (PV reduction axis: NaN*0=NaN);
    // keys >=52 not stored (va reads clamp kg to 12).
    #pragma unroll
    for (int i = 0; i < 2; ++i) {
        #pragma unroll
        for (int nt = 0; nt < 4; ++nt) {
            const int key = nt * 16 + lr;
            if (key < 52) {
                #pragma unroll
                for (int r = 0; r < 4; ++r) {
                    const int d = 16 * i + 4 * lg + r;
                    const unsigned short val =
                        (key < NT_) ? bfbits(accV[i][nt][r]) : (unsigned short)0;
                    *(unsigned short*)(smc + vbh + (key >> 2) * 264 + d * 8 + ((key & 3) << 1)) = val;
                }
            }
        }
    }

    // ka: x16 A-fragments from own K region — MUST complete before b3
    // (other waves' X2 overlays the K region after b3).
    s16x4 ka[2][4];
    #pragma unroll
    for (int kt = 0; kt < 2; ++kt)
        #pragma unroll
        for (int mt = 0; mt < 4; ++mt)
            ka[kt][mt] = *(const s16x4*)(smc + kbh + (4 * kt + lg) * 512 + (mt * 16 + lr) * 8);
    __syncthreads();  // b3: all ka reads done -> X2 overlay of K region safe

    // va stream bases: kg = kt*4+lg clamped to 12 (keys>=52 -> P=0 anyway)
    int vaddr[4];
    #pragma unroll
    for (int kt = 0; kt < 4; ++kt) {
        int kg = kt * 4 + lg; if (kg > 12) kg = 12;
        vaddr[kt] = vbh + kg * 264 + lr * 8;
    }
    const float* cbw = cb + (((size_t)(wi * 8 + wj) * 4 + w) * 49) * 64;

    // ---------------- phase 3: attention (Q/S/P in regs; V streamed) ----------------
    #pragma unroll
    for (int nt = 0; nt < 4; ++nt) {
        f32x4 sn[4];
        #pragma unroll
        for (int mt = 0; mt < 4; ++mt) {
            f32x4 z = {0.f, 0.f, 0.f, 0.f};
            z = __builtin_amdgcn_mfma_f32_16x16x16bf16_1k(ka[0][mt], qf[0][nt], z, 0, 0, 0);
            sn[mt] = __builtin_amdgcn_mfma_f32_16x16x16bf16_1k(ka[1][mt], qf[1][nt], z, 0, 0, 0);
        }
        // softmax over valid keys (key = mt*16 + 4*lg + r < 49)
        float mx = -3.0e38f;
        #pragma unroll
        for (int mt = 0; mt < 3; ++mt)
            #pragma unroll
            for (int r = 0; r < 4; ++r) mx = fmaxf(mx, sn[mt][r]);
        if (lg == 0) mx = fmaxf(mx, sn[3][0]);
        mx = fmaxf(mx, __shfl_xor(mx, 16));
        mx = fmaxf(mx, __shfl_xor(mx, 32));
        float sum = 0.f;
        #pragma unroll
        for (int mt = 0; mt < 3; ++mt)
            #pragma unroll
            for (int r = 0; r < 4; ++r) {
                const float e = __expf(sn[mt][r] - mx);
                sn[mt][r] = e; sum += e;
            }
        {
            const float e = (lg == 0) ? __expf(sn[3][0] - mx) : 0.f;
            sn[3][0] = e;
            sum += e;
        }
        sum += __shfl_xor(sum, 16);
        sum += __shfl_xor(sum, 32);
        const float rs = 1.0f / sum;

        const int q  = nt * 16 + lr;
        const int qc = (q < NT_) ? q : 48;
        const float* cbq = cbw + qc * 64;

        // post-softmax bias+mask; P packs straight into x16 B-fragments (no LDS)
        s16x4 pf[4];
        #pragma unroll
        for (int mt = 0; mt < 4; ++mt) {
            const f32x4 bv = *(const f32x4*)(cbq + mt * 16 + lg * 4);
            union { s16x4 v; __bf16 e[4]; } u;
            #pragma unroll
            for (int r = 0; r < 4; ++r) {
                const bool valid = (mt < 3) || (lg == 0 && r == 0);
                const float p = fmaf(sn[mt][r], rs, bv[r]);
                u.e[r] = valid ? (__bf16)p : (__bf16)0.0f;
            }
            pf[mt] = u.v;
        }
        // PV: stream va, per-nt accumulators only
        f32x4 o0 = {0.f, 0.f, 0.f, 0.f}, o1 = {0.f, 0.f, 0.f, 0.f};
        #pragma unroll
        for (int kt = 0; kt < 4; ++kt) {
            const s16x4 va0 = *(const s16x4*)(smc + vaddr[kt]);
            const s16x4 va1 = *(const s16x4*)(smc + vaddr[kt] + 128);
            o0 = __builtin_amdgcn_mfma_f32_16x16x16bf16_1k(va0, pf[kt], o0, 0, 0, 0);
            o1 = __builtin_amdgcn_mfma_f32_16x16x16bf16_1k(va1, pf[kt], o1, 0, 0, 0);
        }
        // X2 scatter into K region (own head's g-range; safe post-b3)
        if (q < NT_) {
            const int inner = (lg & 1) << 3;
            union { short4 s4; __bf16 e[4]; } pk0, pk1;
            #pragma unroll
            for (int r = 0; r < 4; ++r) { pk0.e[r] = (__bf16)o0[r]; pk1.e[r] = (__bf16)o1[r]; }
            *(short4*)(smc + KB + q4(w * 4 + 0 + (lg >> 1), q) + inner) = pk0.s4;
            *(short4*)(smc + KB + q4(w * 4 + 2 + (lg >> 1), q) + inner) = pk1.s4;
        }
    }
    __syncthreads();  // b4: all heads' X2 complete

    // ---------------- phase 4: proj = X2 @ Wp + store ----------------
    {
        const int* toff = (const int*)(smc + TOFFB);
        f32x4 pacc[4][2];
        #pragma unroll
        for (int ntl = 0; ntl < 2; ++ntl) {
            const float bv = b_proj[(w * 2 + ntl) * 16 + lr];
            #pragma unroll
            for (int mt = 0; mt < 4; ++mt) {
                f32x4 v = {bv, bv, bv, bv};
                pacc[mt][ntl] = v;
            }
        }
        #pragma unroll
        for (int ks = 0; ks < 4; ++ks) {
            bf16x8 af[4];
            #pragma unroll
            for (int mt = 0; mt < 4; ++mt)   // rows>=49: stale K bytes, rows discarded
                af[mt] = *(const bf16x8*)(smc + KB + q4(ks * 4 + lg, mt * 16 + lr));
            #pragma unroll
            for (int ntl = 0; ntl < 2; ++ntl) {
                const bf16x8 bfp = *(const bf16x8*)(wpt + ((w * 2 + ntl) * 16 + lr) * 128 + ks * 32 + lg * 8);
                #pragma unroll
                for (int mt = 0; mt < 4; ++mt)
                    pacc[mt][ntl] = __builtin_amdgcn_mfma_f32_16x16x32_bf16(af[mt], bfp, pacc[mt][ntl], 0, 0, 0);
            }
        }
        #pragma unroll
        for (int mt = 0; mt < 4; ++mt)
            #pragma unroll
            for (int r = 0; r < 4; ++r) {
                const int tok = mt * 16 + lg * 4 + r;
                if (tok < NT_) {
                    float* po = out + (((size_t)b * (HW_ * HW_)) + toff[tok]) * C_;
                    #pragma unroll
                    for (int ntl = 0; ntl < 2; ++ntl)
                        po[(w * 2 + ntl) * 16 + lr] = pacc[mt][ntl][r];
                }
            }
    }
}

extern "C" void kernel_launch(void* const* d_in, const int* in_sizes, int n_in,
                              void* d_out, int out_size, void* d_ws, size_t ws_size,
                              hipStream_t stream) {
    const float* x      = (const float*)d_in[0];
    const float* w_qkv  = (const float*)d_in[1];
    const float* b_qkv  = (const float*)d_in[2];
    const float* w_proj = (const float*)d_in[3];
    const float* b_proj = (const float*)d_in[4];
    const float* rel    = (const float*)d_in[5];
    float* outp = (float*)d_out;
    unsigned short* wsb = (unsigned short*)d_ws;
    float* cbp = (float*)((char*)d_ws + WS_CB_BYTE);

    hipLaunchKernelGGL(prep_weights, dim3(256), dim3(256), 0, stream, w_qkv, w_proj, wsb);
    hipLaunchKernelGGL(prep_bias, dim3((CB_ELEMS + 255) / 256), dim3(256), 0, stream, rel, cbp);
    hipLaunchKernelGGL(swin_fused, dim3(4096), dim3(256), SMEMB, stream,
                       x, b_qkv, b_proj, wsb, cbp, outp);
}

// Round 12
// 96.611 us; speedup vs baseline: 2.1588x; 1.8647x over previous
//
#include <hip/hip_runtime.h>

#define HW_    56
#define C_     128
#define SHIFT_ 3
#define NH_    4
#define NT_    49

typedef __attribute__((ext_vector_type(8))) __bf16 bf16x8;
typedef __attribute__((ext_vector_type(4))) float  f32x4;

// d_ws layout:
//   shorts [0, 65536)      : wt2 (24 qkv oc-tiles) then wp2 (8 proj oc-tiles),
//                            FRAGMENT-CONTIGUOUS: block (tile,ks) = 512 bf16,
//                            lane L holds elems [L*8, L*8+8) = (oc=tile*16+(L&15),
//                            ic=ks*32+(L>>4)*8+e). One wave fragment load =
//                            1KB contiguous (16B/lane, single L2 line set).
//   bytes  [131072, +3.2MB): f32 cb[wpos=64][h=4][q=49][k=64] (bias+mask, post-softmax)
#define WS_CB_BYTE  131072
#define CB_ELEMS    (64 * 4 * 49 * 64)

// LDS 39424 B -> 4 blocks/CU @ 256 thr. (R8 layout, unchanged — proven no-spill.)
// [0, 25088): Q/K per head h at h*6272: Q g=0..3 (+0), K g=0..3 (+3136);
//             P [8 kg][49 q][16B] overlays Q+K after frag preload.
//             Identity 784-B stride: fixed g per quarter-wave -> conflict-free.
// [25088, 39424) = R0 (14336 B):
//   phases 1-2: X [16 g][49 tok][16B] stride 784 (dead at b2)
//   after b2:   per head h at R0+h*3584: V^T [7 oct][32 d][16B] (swzv);
//               keys 49..55 ZERO-FILLED (PV reduction axis: NaN*0=NaN!)
//   after PV:   X2 [4 g][49 tok][16B] stride 784 overlays own head's V.
#define QH    6272
#define R0B   25088
#define VH    3584
#define SMEMB 39424

__device__ __forceinline__ int q4(int g, int tok) {   // identity, stride 784
    return g * 784 + (tok << 4);
}
__device__ __forceinline__ int p8(int kg, int q) {    // identity, stride 784
    return kg * 784 + (q << 4);
}
__device__ __forceinline__ int swzv(int g, int row) { // V: pow2 rows, g-XOR ok
    return (((g << 9) + (row << 4)) ^ ((g & 7) << 4));
}
__device__ __forceinline__ unsigned short bfbits(float f) {
    __bf16 h = (__bf16)f;
    union { __bf16 b; unsigned short u; } c; c.b = h; return c.u;
}
__device__ __forceinline__ int region(int c) { return c < 49 ? 0 : (c < 53 ? 1 : 2); }

// ---- prep 1: weights -> bf16, fragment-contiguous tiles ----
// wt2 block (mt,ks), mt 0..23: i = (mt*4+ks)*512 + lane*8 + e
// wp2 block (t,ks),  t  0..7 : j = (t*4+ks)*512 + lane*8 + e  (at +49152)
__global__ void prep_weights(const float* __restrict__ wq, const float* __restrict__ wp,
                             unsigned short* __restrict__ ws) {
    int i = blockIdx.x * 256 + threadIdx.x;
    if (i < 49152) {
        const int mt   = i >> 11;
        const int ks   = (i >> 9) & 3;
        const int lane = (i >> 3) & 63;
        const int e    = i & 7;
        const int oc   = mt * 16 + (lane & 15);
        const int ic   = ks * 32 + (lane >> 4) * 8 + e;
        ws[i] = bfbits(wq[ic * 384 + oc]);
    } else if (i < 65536) {
        const int j    = i - 49152;
        const int t    = j >> 11;
        const int ks   = (j >> 9) & 3;
        const int lane = (j >> 3) & 63;
        const int e    = j & 7;
        const int oc   = t * 16 + (lane & 15);
        const int ic   = ks * 32 + (lane >> 4) * 8 + e;
        ws[i] = bfbits(wp[ic * 128 + oc]);
    }
}

// ---- prep 2: combined post-softmax bias + shifted-window mask ----
__global__ void prep_bias(const float* __restrict__ rel_table, float* __restrict__ cb) {
    int i = blockIdx.x * 256 + threadIdx.x;
    if (i >= CB_ELEMS) return;
    int k = i & 63;
    int t = i >> 6;          // (wpos*4 + h)*49 + q
    int q = t % 49;
    int u = t / 49;
    int h = u & 3;
    int wpos = u >> 2;
    float v = 0.f;
    if (k < 49) {
        int iq = q / 7, jq = q - 7 * iq;
        int ik = k / 7, jk = k - 7 * ik;
        int wi = wpos >> 3, wj = wpos & 7;
        v = rel_table[((iq - ik + 6) * 13 + (jq - jk + 6)) * NH_ + h];
        int rq = region(wi * 7 + iq) * 3 + region(wj * 7 + jq);
        int rk = region(wi * 7 + ik) * 3 + region(wj * 7 + jk);
        if (rq != rk) v -= 100.0f;
    }
    cb[i] = v;
}

__global__ __launch_bounds__(256, 4)
void swin_fused(const float* __restrict__ x,
                const float* __restrict__ b_qkv,
                const float* __restrict__ b_proj,
                const unsigned short* __restrict__ wsb,
                const float* __restrict__ cb,
                float* __restrict__ out)
{
    extern __shared__ char smc[];
    const __bf16* wt2 = (const __bf16*)wsb;           // 24 frag-tiles
    const __bf16* wp2 = (const __bf16*)(wsb + 49152); // 8 frag-tiles

    const int tid = threadIdx.x;
    const int bn  = blockIdx.x;
    const int b   = bn >> 6;
    const int wi  = (bn >> 3) & 7;
    const int wj  = bn & 7;

    const int w  = tid >> 6;        // wave id 0..3
    const int lr = tid & 15;        // lane % 16
    const int lg = (tid & 63) >> 4; // lane / 16
    const int ln = tid & 63;        // lane in wave

    // ---------------- phase 1: x -> X (bf16 frag-order, 49 rows) ----------------
    for (int idx = tid; idx < 49 * 16; idx += 256) {
        const int g = idx & 15, tok = idx >> 4;
        const int i1 = tok / 7, j1 = tok - 7 * i1;
        int gh = wi * 7 + i1 + SHIFT_; if (gh >= HW_) gh -= HW_;
        int gw = wj * 7 + j1 + SHIFT_; if (gw >= HW_) gw -= HW_;
        const float* px = x + (((size_t)(b * HW_ + gh)) * HW_ + gw) * C_ + g * 8;
        float4 a0 = *(const float4*)(px);
        float4 a1 = *(const float4*)(px + 4);
        union { bf16x8 v; __bf16 e[8]; } u;
        u.e[0] = (__bf16)a0.x; u.e[1] = (__bf16)a0.y;
        u.e[2] = (__bf16)a0.z; u.e[3] = (__bf16)a0.w;
        u.e[4] = (__bf16)a1.x; u.e[5] = (__bf16)a1.y;
        u.e[6] = (__bf16)a1.z; u.e[7] = (__bf16)a1.w;
        *(bf16x8*)(smc + R0B + q4(g, tok)) = u.v;
    }
    __syncthreads();  // b1

    // ---------------- phase 2: QKV' = Wt @ X^T, two 3-tile passes ----------------
    // wave w owns oc-tiles mt = w + 4*i, i=0..5: {q,q,k,k,v,v}
    const float qscale = 0.17677669529663687f;
    f32x4 accV[2][4];   // v tiles survive past b2

    #pragma unroll
    for (int pass = 0; pass < 2; ++pass) {
        f32x4 acc[3][4];
        #pragma unroll
        for (int i = 0; i < 3; ++i) {
            const int mt = w + 4 * (pass * 3 + i);
            const f32x4 bv = *(const f32x4*)(b_qkv + mt * 16 + lg * 4);
            #pragma unroll
            for (int nt = 0; nt < 4; ++nt) acc[i][nt] = bv;
        }
        #pragma unroll
        for (int ks = 0; ks < 4; ++ks) {
            bf16x8 bfr[4];
            #pragma unroll
            for (int nt = 0; nt < 4; ++nt)   // tok>=49 reads in-bounds garbage; cols discarded
                bfr[nt] = *(const bf16x8*)(smc + R0B + q4(ks * 4 + lg, nt * 16 + lr));
            __builtin_amdgcn_s_setprio(1);
            #pragma unroll
            for (int i = 0; i < 3; ++i) {
                const int mt = w + 4 * (pass * 3 + i);
                bf16x8 afr = *(const bf16x8*)(wt2 + ((mt * 4 + ks) << 9) + (ln << 3));
                #pragma unroll
                for (int nt = 0; nt < 4; ++nt)
                    acc[i][nt] = __builtin_amdgcn_mfma_f32_16x16x32_bf16(afr, bfr[nt], acc[i][nt], 0, 0, 0);
            }
            __builtin_amdgcn_s_setprio(0);
        }
        // scatter q/k tiles now; keep v tiles in regs
        #pragma unroll
        for (int i = 0; i < 3; ++i) {
            const int ti = pass * 3 + i;
            const int mt = w + 4 * ti;
            if (ti < 4) {                       // q (ti 0,1) / k (ti 2,3)
                const int which = mt >> 3;
                const int hd    = (mt >> 1) & 3;
                const int d0    = ((mt & 1) << 4) + lg * 4;
                const float sc  = (which == 0) ? qscale : 1.0f;
                const int base  = hd * QH + which * 3136;
                const int g = d0 >> 3, inner = (d0 & 4) << 1;
                #pragma unroll
                for (int nt = 0; nt < 4; ++nt) {
                    const int tok = nt * 16 + lr;
                    if (tok < NT_) {
                        union { short4 s4; __bf16 e[4]; } pk;
                        #pragma unroll
                        for (int r = 0; r < 4; ++r) pk.e[r] = (__bf16)(acc[i][nt][r] * sc);
                        *(short4*)(smc + base + q4(g, tok) + inner) = pk.s4;
                    }
                }
            } else {                            // v (ti 4,5): stash
                #pragma unroll
                for (int nt = 0; nt < 4; ++nt) accV[ti - 4][nt] = acc[i][nt];
            }
        }
    }
    __syncthreads();  // b2: X reads done; Q/K published

    // V scatter into R0 (X dead). Keys 49..55 ZERO-FILLED (PV reduction axis).
    {
        #pragma unroll
        for (int t = 0; t < 2; ++t) {
            const int mt = w + 4 * (4 + t);
            const int hv = (mt >> 1) & 3;
            const int d0 = ((mt & 1) << 4) + lg * 4;
            const int vb2 = R0B + hv * VH;
            #pragma unroll
            for (int nt = 0; nt < 4; ++nt) {
                const int tok = nt * 16 + lr;
                if (tok < 56) {
                    #pragma unroll
                    for (int r = 0; r < 4; ++r) {
                        const unsigned short val =
                            (tok < NT_) ? bfbits(accV[t][nt][r]) : (unsigned short)0;
                        *(unsigned short*)(smc + vb2 + swzv(tok >> 3, d0 + r) + ((tok & 7) << 1)) = val;
                    }
                }
            }
        }
    }

    // ---------------- phase 3: attention, wave = head ----------------
    const int h   = w;
    const int qb_ = h * QH;
    const int kb_ = qb_ + 3136;
    const int vb_ = R0B + h * VH;
    const float* cbw = cb + (((size_t)(wi * 8 + wj) * 4 + h) * 49) * 64;

    // preload K/Q fragments (reads Q/K published at b2; P overlay comes after b3)
    bf16x8 ka[4], qf[4];
    #pragma unroll
    for (int mt = 0; mt < 4; ++mt)
        ka[mt] = *(const bf16x8*)(smc + kb_ + q4(lg, mt * 16 + lr));
    #pragma unroll
    for (int nt = 0; nt < 4; ++nt)
        qf[nt] = *(const bf16x8*)(smc + qb_ + q4(lg, nt * 16 + lr));
    __syncthreads();  // b3: V published; all ka/qf preloads done -> P overlay safe

    {
        // S^T = K @ Q^T  (keys x q, K=32)
        f32x4 s[4][4];
        __builtin_amdgcn_s_setprio(1);
        #pragma unroll
        for (int mt = 0; mt < 4; ++mt)
            #pragma unroll
            for (int nt = 0; nt < 4; ++nt) {
                f32x4 z = {0.f, 0.f, 0.f, 0.f};
                s[mt][nt] = __builtin_amdgcn_mfma_f32_16x16x32_bf16(ka[mt], qf[nt], z, 0, 0, 0);
            }
        __builtin_amdgcn_s_setprio(0);

        // softmax over keys + post-softmax (bias+mask) from cb -> P (overlays Q+K)
        #pragma unroll
        for (int nt = 0; nt < 4; ++nt) {
            float mx = -3.0e38f;
            #pragma unroll
            for (int mt = 0; mt < 3; ++mt)
                #pragma unroll
                for (int r = 0; r < 4; ++r) mx = fmaxf(mx, s[mt][nt][r]);
            if (lg == 0) mx = fmaxf(mx, s[3][nt][0]);
            mx = fmaxf(mx, __shfl_xor(mx, 16));
            mx = fmaxf(mx, __shfl_xor(mx, 32));
            float sum = 0.f;
            #pragma unroll
            for (int mt = 0; mt < 3; ++mt)
                #pragma unroll
                for (int r = 0; r < 4; ++r) {
                    const float e = __expf(s[mt][nt][r] - mx);
                    s[mt][nt][r] = e; sum += e;
                }
            {
                const float e = (lg == 0) ? __expf(s[3][nt][0] - mx) : 0.f;
                s[3][nt][0] = e;
                sum += e;
            }
            sum += __shfl_xor(sum, 16);
            sum += __shfl_xor(sum, 32);
            const float rs = 1.0f / sum;

            const int q  = nt * 16 + lr;
            const int qc = (q < NT_) ? q : 48;
            const float* cbq = cbw + qc * 64;

            if (q < NT_) {
                const int inner = (lg & 1) << 3;
                #pragma unroll
                for (int mt = 0; mt < 4; ++mt) {
                    const f32x4 bv = *(const f32x4*)(cbq + mt * 16 + lg * 4);
                    union { short4 s4; __bf16 e[4]; } pk;
                    #pragma unroll
                    for (int r = 0; r < 4; ++r) {
                        const bool valid = (mt < 3) || (lg == 0 && r == 0);
                        const float p = fmaf(s[mt][nt][r], rs, bv[r]);
                        pk.e[r] = valid ? (__bf16)p : (__bf16)0.0f;
                    }
                    *(short4*)(smc + qb_ + p8(2 * mt + (lg >> 1), q) + inner) = pk.s4;
                }
            }
        }

        // O^T = VT @ P^T  (d x q, K=64 keys) -> X2 overlays own head's V
        f32x4 o[2][4];
        #pragma unroll
        for (int mtd = 0; mtd < 2; ++mtd)
            #pragma unroll
            for (int nt = 0; nt < 4; ++nt) { f32x4 z = {0.f,0.f,0.f,0.f}; o[mtd][nt] = z; }
        #pragma unroll
        for (int ks = 0; ks < 2; ++ks) {
            bf16x8 va[2], pf[4];
            #pragma unroll
            for (int mtd = 0; mtd < 2; ++mtd) {
                if (ks * 4 + lg == 7) {
                    union { bf16x8 v; __bf16 e[8]; } z;
                    #pragma unroll
                    for (int e = 0; e < 8; ++e) z.e[e] = (__bf16)0.0f;
                    va[mtd] = z.v;                       // keys 56..63 don't exist
                } else {
                    va[mtd] = *(const bf16x8*)(smc + vb_ + swzv(ks * 4 + lg, mtd * 16 + lr));
                }
            }
            #pragma unroll
            for (int nt = 0; nt < 4; ++nt)
                pf[nt] = *(const bf16x8*)(smc + qb_ + p8(ks * 4 + lg, nt * 16 + lr));
            __builtin_amdgcn_s_setprio(1);
            #pragma unroll
            for (int mtd = 0; mtd < 2; ++mtd)
                #pragma unroll
                for (int nt = 0; nt < 4; ++nt)
                    o[mtd][nt] = __builtin_amdgcn_mfma_f32_16x16x32_bf16(va[mtd], pf[nt], o[mtd][nt], 0, 0, 0);
            __builtin_amdgcn_s_setprio(0);
        }
        // X2 scatter into own V region (this wave's V reads are done)
        #pragma unroll
        for (int mtd = 0; mtd < 2; ++mtd) {
            const int gl = (mtd * 2 + (lg >> 1)) & 3;
            const int inner = (lg & 1) << 3;
            #pragma unroll
            for (int nt = 0; nt < 4; ++nt) {
                const int tok = nt * 16 + lr;
                if (tok < NT_) {
                    union { short4 s4; __bf16 e[4]; } pk;
                    #pragma unroll
                    for (int r = 0; r < 4; ++r) pk.e[r] = (__bf16)o[mtd][nt][r];
                    *(short4*)(smc + vb_ + q4(gl, tok) + inner) = pk.s4;
                }
            }
        }
    }

    // hoist proj weight fragments (global, no LDS dep) before the barrier
    bf16x8 bfpR[2][4];
    #pragma unroll
    for (int ntl = 0; ntl < 2; ++ntl)
        #pragma unroll
        for (int ks = 0; ks < 4; ++ks)
            bfpR[ntl][ks] = *(const bf16x8*)(wp2 + (((w * 2 + ntl) * 4 + ks) << 9) + (ln << 3));
    __syncthreads();  // b4: all X2 complete

    // ---------------- phase 4: proj = X2 @ Wp + store ----------------
    {
        f32x4 pacc[4][2];
        #pragma unroll
        for (int ntl = 0; ntl < 2; ++ntl) {
            const float bv = b_proj[(w * 2 + ntl) * 16 + lr];
            #pragma unroll
            for (int mt = 0; mt < 4; ++mt) {
                f32x4 v = {bv, bv, bv, bv};
                pacc[mt][ntl] = v;
            }
        }
        #pragma unroll
        for (int ks = 0; ks < 4; ++ks) {
            bf16x8 af[4];
            const int g = ks * 4 + lg;
            #pragma unroll
            for (int mt = 0; mt < 4; ++mt)
                af[mt] = *(const bf16x8*)(smc + R0B + (g >> 2) * VH + q4(g & 3, mt * 16 + lr));
            __builtin_amdgcn_s_setprio(1);
            #pragma unroll
            for (int mt = 0; mt < 4; ++mt)
                #pragma unroll
                for (int ntl = 0; ntl < 2; ++ntl)
                    pacc[mt][ntl] = __builtin_amdgcn_mfma_f32_16x16x32_bf16(af[mt], bfpR[ntl][ks], pacc[mt][ntl], 0, 0, 0);
            __builtin_amdgcn_s_setprio(0);
        }
        #pragma unroll
        for (int mt = 0; mt < 4; ++mt)
            #pragma unroll
            for (int r = 0; r < 4; ++r) {
                const int tok = mt * 16 + lg * 4 + r;
                if (tok < NT_) {
                    const int i1 = tok / 7, j1 = tok - 7 * i1;
                    int gh = wi * 7 + i1 + SHIFT_; if (gh >= HW_) gh -= HW_;
                    int gw = wj * 7 + j1 + SHIFT_; if (gw >= HW_) gw -= HW_;
                    float* po = out + (((size_t)(b * HW_ + gh)) * HW_ + gw) * C_;
                    #pragma unroll
                    for (int ntl = 0; ntl < 2; ++ntl)
                        po[(w * 2 + ntl) * 16 + lr] = pacc[mt][ntl][r];
                }
            }
    }
}

extern "C" void kernel_launch(void* const* d_in, const int* in_sizes, int n_in,
                              void* d_out, int out_size, void* d_ws, size_t ws_size,
                              hipStream_t stream) {
    const float* x      = (const float*)d_in[0];
    const float* w_qkv  = (const float*)d_in[1];
    const float* b_qkv  = (const float*)d_in[2];
    const float* w_proj = (const float*)d_in[3];
    const float* b_proj = (const float*)d_in[4];
    const float* rel    = (const float*)d_in[5];
    float* outp = (float*)d_out;
    unsigned short* wsb = (unsigned short*)d_ws;
    float* cbp = (float*)((char*)d_ws + WS_CB_BYTE);

    hipLaunchKernelGGL(prep_weights, dim3(256), dim3(256), 0, stream, w_qkv, w_proj, wsb);
    hipLaunchKernelGGL(prep_bias, dim3((CB_ELEMS + 255) / 256), dim3(256), 0, stream, rel, cbp);
    hipLaunchKernelGGL(swin_fused, dim3(4096), dim3(256), SMEMB, stream,
                       x, b_qkv, b_proj, wsb, cbp, outp);
}

// Round 13
// 85.247 us; speedup vs baseline: 2.4466x; 1.1333x over previous
//
#include <hip/hip_runtime.h>

#define HW_    56
#define C_     128
#define SHIFT_ 3
#define NH_    4
#define NT_    49

typedef __attribute__((ext_vector_type(8))) __bf16 bf16x8;
typedef __attribute__((ext_vector_type(4))) float  f32x4;
typedef __attribute__((ext_vector_type(4))) short  s16x4;

// d_ws layout:
//   shorts [0, 65536)       : wt2 (24 qkv oc-tiles) then wp2 (8 proj oc-tiles),
//                             FRAGMENT-CONTIGUOUS (R12): block (tile,ks)=512 bf16,
//                             lane L holds (oc=tile*16+(L&15), ic=ks*32+(L>>4)*8+e).
//   bytes [131072, +200704) : f32 cb[cls=4][h=4][q=49][k=64] — bias+mask
//                             (post-softmax). Mask depends ONLY on (wi==7,wj==7):
//                             rows 0..48 are region 0; wi==7 rows are 49+i1
//                             (region 1 for i1<4, else 2). cls=2*(wi==7)+(wj==7).
#define WS_CB_BYTE  131072
#define CB_ELEMS    (4 * 4 * 49 * 64)

// LDS 29440 B, (256,4) -> LDS permits 5 blocks/CU; regs decide.
// [0, 12800):  X [16 g][49 tok][16B] stride 784 identity (fixed g per
//   quarter-wave -> conflict-free). Reads to tok 63 reach 12768 < 12800:
//   in-bounds garbage (possibly NaN) feeding ONLY discarded rows/cols —
//   audited: qf cols>=49 (skipped via q<NT_), ka rows>=49 (pf forced 0),
//   phase-4 af rows>=49 (store skipped). After b2: X2 overlays, same layout,
//   head h owns g=4h..4h+3.
// [12800, 29184): V per head h at VB+h*4096: [8 oct][32 d][16B] swzv; ALL
//   octs written, keys 49..63 ZERO (PV reduction axis: NaN*0=NaN!). Private
//   per wave: write (phase2) -> read (phase3) same-wave, no barrier.
// [29184, 29380): int toff[49].
// Q,K,S,P: REGISTER-RESIDENT. x32 C-layout chunk (4 consecutive oc per lane,
// token=lr) IS the x16 A/B fragment (row/col=lr, k=4*lg+j) — R9-validated.
#define XB    0
#define VB    12800
#define TOFFB 29184
#define SMEMB 29440

__device__ __forceinline__ int q4(int g, int tok) { return g * 784 + (tok << 4); }
__device__ __forceinline__ int swzv(int g, int row) {
    return (((g << 9) + (row << 4)) ^ ((g & 7) << 4));
}
__device__ __forceinline__ unsigned short bfbits(float f) {
    __bf16 h = (__bf16)f;
    union { __bf16 b; unsigned short u; } c; c.b = h; return c.u;
}

// ---- fused prep: weights (frag-contiguous bf16) + cb class table ----
__global__ void prep(const float* __restrict__ wq, const float* __restrict__ wp,
                     const float* __restrict__ rel, unsigned short* __restrict__ ws,
                     float* __restrict__ cb) {
    int i = blockIdx.x * 256 + threadIdx.x;
    if (i < 49152) {
        const int mt   = i >> 11;
        const int ks   = (i >> 9) & 3;
        const int lane = (i >> 3) & 63;
        const int e    = i & 7;
        const int oc   = mt * 16 + (lane & 15);
        const int ic   = ks * 32 + (lane >> 4) * 8 + e;
        ws[i] = bfbits(wq[ic * 384 + oc]);
    } else if (i < 65536) {
        const int j    = i - 49152;
        const int t    = j >> 11;
        const int ks   = (j >> 9) & 3;
        const int lane = (j >> 3) & 63;
        const int e    = j & 7;
        const int oc   = t * 16 + (lane & 15);
        const int ic   = ks * 32 + (lane >> 4) * 8 + e;
        ws[i] = bfbits(wp[ic * 128 + oc]);
    } else {
        const int j = i - 65536;
        if (j < CB_ELEMS) {
            const int k = j & 63;
            const int t = j >> 6;          // (cls*4 + h)*49 + q
            const int q = t % 49;
            const int u = t / 49;
            const int h = u & 3;
            const int cls = u >> 2;        // 2*(wi==7) + (wj==7)
            float v = 0.f;
            if (k < 49) {
                const int iq = q / 7, jq = q - 7 * iq;
                const int ik = k / 7, jk = k - 7 * ik;
                v = rel[((iq - ik + 6) * 13 + (jq - jk + 6)) * NH_ + h];
                const int rq = ((cls >> 1) ? (iq < 4 ? 1 : 2) : 0) * 3
                             + ((cls & 1) ? (jq < 4 ? 1 : 2) : 0);
                const int rk = ((cls >> 1) ? (ik < 4 ? 1 : 2) : 0) * 3
                             + ((cls & 1) ? (jk < 4 ? 1 : 2) : 0);
                if (rq != rk) v -= 100.0f;
            }
            cb[j] = v;
        }
    }
}

__global__ __launch_bounds__(256, 4)
void swin_fused(const float* __restrict__ x,
                const float* __restrict__ b_qkv,
                const float* __restrict__ b_proj,
                const unsigned short* __restrict__ wsb,
                const float* __restrict__ cb,
                float* __restrict__ out)
{
    extern __shared__ char smc[];
    const __bf16* wt2 = (const __bf16*)wsb;           // 24 frag-tiles
    const __bf16* wp2 = (const __bf16*)(wsb + 49152); // 8 frag-tiles

    const int tid = threadIdx.x;
    const int bn  = blockIdx.x;
    const int b   = bn >> 6;
    const int wi  = (bn >> 3) & 7;
    const int wj  = bn & 7;

    const int w  = tid >> 6;        // wave id = head id
    const int lr = tid & 15;        // lane % 16
    const int lg = (tid & 63) >> 4; // lane / 16
    const int ln = tid & 63;        // lane in wave

    // token -> rolled spatial offset table (used by epilogue)
    if (tid < NT_) {
        const int i1 = tid / 7, j1 = tid - 7 * i1;
        int gh = wi * 7 + i1 + SHIFT_; if (gh >= HW_) gh -= HW_;
        int gw = wj * 7 + j1 + SHIFT_; if (gw >= HW_) gw -= HW_;
        ((int*)(smc + TOFFB))[tid] = gh * HW_ + gw;
    }

    // ---------------- phase 1: x -> X (bf16 frag-order, 49 rows) ----------------
    for (int idx = tid; idx < 49 * 16; idx += 256) {
        const int g = idx & 15, tok = idx >> 4;
        const int i1 = tok / 7, j1 = tok - 7 * i1;
        int gh = wi * 7 + i1 + SHIFT_; if (gh >= HW_) gh -= HW_;
        int gw = wj * 7 + j1 + SHIFT_; if (gw >= HW_) gw -= HW_;
        const float* px = x + (((size_t)(b * HW_ + gh)) * HW_ + gw) * C_ + g * 8;
        float4 a0 = *(const float4*)(px);
        float4 a1 = *(const float4*)(px + 4);
        union { bf16x8 v; __bf16 e[8]; } u;
        u.e[0] = (__bf16)a0.x; u.e[1] = (__bf16)a0.y;
        u.e[2] = (__bf16)a0.z; u.e[3] = (__bf16)a0.w;
        u.e[4] = (__bf16)a1.x; u.e[5] = (__bf16)a1.y;
        u.e[6] = (__bf16)a1.z; u.e[7] = (__bf16)a1.w;
        *(bf16x8*)(smc + XB + q4(g, tok)) = u.v;
    }
    __syncthreads();  // b1: X (and toff) ready

    // ---------------- phase 2: QKV, wave w owns head w; Q/K -> x16 reg frags ----------------
    // pass0: q tiles {2w, 2w+1} -> qf. pass1: k tiles {8+2w, 8+2w+1} -> ka.
    // pass2: v tiles {16+2w, 16+2w+1} -> V LDS (standalone region, immediate).
    const float qscale = 0.17677669529663687f;
    const int vb = VB + w * 4096;
    s16x4 qf[2][4], ka[2][4];   // elem j = d offset 4*lg+j within 16-d tile

    #pragma unroll
    for (int pass = 0; pass < 3; ++pass) {
        const int mt0 = pass * 8 + 2 * w;
        f32x4 acc[2][4];
        #pragma unroll
        for (int i = 0; i < 2; ++i) {
            const f32x4 bv = *(const f32x4*)(b_qkv + (mt0 + i) * 16 + lg * 4);
            #pragma unroll
            for (int nt = 0; nt < 4; ++nt) acc[i][nt] = bv;
        }
        #pragma unroll
        for (int ks = 0; ks < 4; ++ks) {
            bf16x8 bfr[4];
            #pragma unroll
            for (int nt = 0; nt < 4; ++nt)   // tok>=49: in-bounds garbage, isolated (see map)
                bfr[nt] = *(const bf16x8*)(smc + XB + q4(ks * 4 + lg, nt * 16 + lr));
            __builtin_amdgcn_s_setprio(1);
            #pragma unroll
            for (int i = 0; i < 2; ++i) {
                bf16x8 afr = *(const bf16x8*)(wt2 + (((mt0 + i) * 4 + ks) << 9) + (ln << 3));
                #pragma unroll
                for (int nt = 0; nt < 4; ++nt)
                    acc[i][nt] = __builtin_amdgcn_mfma_f32_16x16x32_bf16(afr, bfr[nt], acc[i][nt], 0, 0, 0);
            }
            __builtin_amdgcn_s_setprio(0);
        }
        if (pass == 0) {            // Q -> x16 B-frags (scaled)
            #pragma unroll
            for (int i = 0; i < 2; ++i)
                #pragma unroll
                for (int nt = 0; nt < 4; ++nt) {
                    union { s16x4 v; __bf16 e[4]; } u;
                    #pragma unroll
                    for (int r = 0; r < 4; ++r) u.e[r] = (__bf16)(acc[i][nt][r] * qscale);
                    qf[i][nt] = u.v;
                }
        } else if (pass == 1) {     // K -> x16 A-frags
            #pragma unroll
            for (int i = 0; i < 2; ++i)
                #pragma unroll
                for (int nt = 0; nt < 4; ++nt) {
                    union { s16x4 v; __bf16 e[4]; } u;
                    #pragma unroll
                    for (int r = 0; r < 4; ++r) u.e[r] = (__bf16)acc[i][nt][r];
                    ka[i][nt] = u.v;
                }
        } else {                    // V -> own LDS region; keys 49..63 ZERO
            #pragma unroll
            for (int i = 0; i < 2; ++i)
                #pragma unroll
                for (int nt = 0; nt < 4; ++nt) {
                    const int tok = nt * 16 + lr;
                    #pragma unroll
                    for (int r = 0; r < 4; ++r) {
                        const int d = i * 16 + lg * 4 + r;
                        const unsigned short val =
                            (tok < NT_) ? bfbits(acc[i][nt][r]) : (unsigned short)0;
                        *(unsigned short*)(smc + vb + swzv(tok >> 3, d) + ((tok & 7) << 1)) = val;
                    }
                }
        }
    }

    // va preload (own V, same-wave write->read): x16 A-frags (d=mtd*16+lr, key=kt*16+4lg+j)
    s16x4 va[2][4];
    #pragma unroll
    for (int mtd = 0; mtd < 2; ++mtd)
        #pragma unroll
        for (int kt = 0; kt < 4; ++kt)
            va[mtd][kt] = *(const s16x4*)(smc + vb
                + swzv(kt * 2 + (lg >> 1), mtd * 16 + lr) + ((lg & 1) << 3));

    __syncthreads();  // b2: all waves' X reads done -> X2 overlay of X safe

    // ---------------- phase 3: attention, fully register-resident ----------------
    const int cls = ((wi == 7) ? 2 : 0) | ((wj == 7) ? 1 : 0);
    const float* cbw = cb + (((size_t)(cls * 4 + w)) * 49) * 64;

    #pragma unroll
    for (int nt = 0; nt < 4; ++nt) {
        // S^T column tile (keys x q), K=16 MFMAs on reg fragments
        f32x4 sn[4];
        __builtin_amdgcn_s_setprio(1);
        #pragma unroll
        for (int mt = 0; mt < 4; ++mt) {
            f32x4 z = {0.f, 0.f, 0.f, 0.f};
            z = __builtin_amdgcn_mfma_f32_16x16x16bf16_1k(ka[0][mt], qf[0][nt], z, 0, 0, 0);
            sn[mt] = __builtin_amdgcn_mfma_f32_16x16x16bf16_1k(ka[1][mt], qf[1][nt], z, 0, 0, 0);
        }
        __builtin_amdgcn_s_setprio(0);
        // softmax over valid keys (key = mt*16 + 4*lg + r < 49)
        float mx = -3.0e38f;
        #pragma unroll
        for (int mt = 0; mt < 3; ++mt)
            #pragma unroll
            for (int r = 0; r < 4; ++r) mx = fmaxf(mx, sn[mt][r]);
        if (lg == 0) mx = fmaxf(mx, sn[3][0]);
        mx = fmaxf(mx, __shfl_xor(mx, 16));
        mx = fmaxf(mx, __shfl_xor(mx, 32));
        float sum = 0.f;
        #pragma unroll
        for (int mt = 0; mt < 3; ++mt)
            #pragma unroll
            for (int r = 0; r < 4; ++r) {
                const float e = __expf(sn[mt][r] - mx);
                sn[mt][r] = e; sum += e;
            }
        {
            const float e = (lg == 0) ? __expf(sn[3][0] - mx) : 0.f;
            sn[3][0] = e;
            sum += e;
        }
        sum += __shfl_xor(sum, 16);
        sum += __shfl_xor(sum, 32);
        const float rs = 1.0f / sum;

        const int q  = nt * 16 + lr;
        const int qc = (q < NT_) ? q : 48;
        const float* cbq = cbw + qc * 64;

        // post-softmax bias+mask; P packs straight into x16 B-frags (no LDS)
        s16x4 pf[4];
        #pragma unroll
        for (int mt = 0; mt < 4; ++mt) {
            const f32x4 bv = *(const f32x4*)(cbq + mt * 16 + lg * 4);
            union { s16x4 v; __bf16 e[4]; } u;
            #pragma unroll
            for (int r = 0; r < 4; ++r) {
                const bool valid = (mt < 3) || (lg == 0 && r == 0);
                const float p = fmaf(sn[mt][r], rs, bv[r]);
                u.e[r] = valid ? (__bf16)p : (__bf16)0.0f;
            }
            pf[mt] = u.v;
        }
        // PV, per-nt accumulators
        f32x4 o0 = {0.f, 0.f, 0.f, 0.f}, o1 = {0.f, 0.f, 0.f, 0.f};
        __builtin_amdgcn_s_setprio(1);
        #pragma unroll
        for (int kt = 0; kt < 4; ++kt) {
            o0 = __builtin_amdgcn_mfma_f32_16x16x16bf16_1k(va[0][kt], pf[kt], o0, 0, 0, 0);
            o1 = __builtin_amdgcn_mfma_f32_16x16x16bf16_1k(va[1][kt], pf[kt], o1, 0, 0, 0);
        }
        __builtin_amdgcn_s_setprio(0);
        // X2 scatter into X region (own head's g-range 4w..4w+3; safe post-b2)
        if (q < NT_) {
            const int inner = (lg & 1) << 3;
            union { short4 s4; __bf16 e[4]; } pk0, pk1;
            #pragma unroll
            for (int r = 0; r < 4; ++r) { pk0.e[r] = (__bf16)o0[r]; pk1.e[r] = (__bf16)o1[r]; }
            *(short4*)(smc + XB + q4(w * 4 + 0 + (lg >> 1), q) + inner) = pk0.s4;
            *(short4*)(smc + XB + q4(w * 4 + 2 + (lg >> 1), q) + inner) = pk1.s4;
        }
    }

    // hoist proj weight fragments (global, no LDS dep) before the barrier
    bf16x8 bfpR[2][4];
    #pragma unroll
    for (int ntl = 0; ntl < 2; ++ntl)
        #pragma unroll
        for (int ks = 0; ks < 4; ++ks)
            bfpR[ntl][ks] = *(const bf16x8*)(wp2 + (((w * 2 + ntl) * 4 + ks) << 9) + (ln << 3));
    __syncthreads();  // b3: all heads' X2 complete

    // ---------------- phase 4: proj = X2 @ Wp + store ----------------
    {
        const int* toff = (const int*)(smc + TOFFB);
        f32x4 pacc[4][2];
        #pragma unroll
        for (int ntl = 0; ntl < 2; ++ntl) {
            const float bv = b_proj[(w * 2 + ntl) * 16 + lr];
            #pragma unroll
            for (int mt = 0; mt < 4; ++mt) {
                f32x4 v = {bv, bv, bv, bv};
                pacc[mt][ntl] = v;
            }
        }
        #pragma unroll
        for (int ks = 0; ks < 4; ++ks) {
            bf16x8 af[4];
            #pragma unroll
            for (int mt = 0; mt < 4; ++mt)   // rows>=49: garbage, rows discarded
                af[mt] = *(const bf16x8*)(smc + XB + q4(ks * 4 + lg, mt * 16 + lr));
            __builtin_amdgcn_s_setprio(1);
            #pragma unroll
            for (int mt = 0; mt < 4; ++mt)
                #pragma unroll
                for (int ntl = 0; ntl < 2; ++ntl)
                    pacc[mt][ntl] = __builtin_amdgcn_mfma_f32_16x16x32_bf16(af[mt], bfpR[ntl][ks], pacc[mt][ntl], 0, 0, 0);
            __builtin_amdgcn_s_setprio(0);
        }
        #pragma unroll
        for (int mt = 0; mt < 4; ++mt)
            #pragma unroll
            for (int r = 0; r < 4; ++r) {
                const int tok = mt * 16 + lg * 4 + r;
                if (tok < NT_) {
                    float* po = out + (((size_t)b * (HW_ * HW_)) + toff[tok]) * C_;
                    #pragma unroll
                    for (int ntl = 0; ntl < 2; ++ntl)
                        po[(w * 2 + ntl) * 16 + lr] = pacc[mt][ntl][r];
                }
            }
    }
}

extern "C" void kernel_launch(void* const* d_in, const int* in_sizes, int n_in,
                              void* d_out, int out_size, void* d_ws, size_t ws_size,
                              hipStream_t stream) {
    const float* x      = (const float*)d_in[0];
    const float* w_qkv  = (const float*)d_in[1];
    const float* b_qkv  = (const float*)d_in[2];
    const float* w_proj = (const float*)d_in[3];
    const float* b_proj = (const float*)d_in[4];
    const float* rel    = (const float*)d_in[5];
    float* outp = (float*)d_out;
    unsigned short* wsb = (unsigned short*)d_ws;
    float* cbp = (float*)((char*)d_ws + WS_CB_BYTE);

    hipLaunchKernelGGL(prep, dim3((65536 + CB_ELEMS + 255) / 256), dim3(256), 0, stream,
                       w_qkv, w_proj, rel, wsb, cbp);
    hipLaunchKernelGGL(swin_fused, dim3(4096), dim3(256), SMEMB, stream,
                       x, b_qkv, b_proj, wsb, cbp, outp);
}